// Round 1
// baseline (410.195 us; speedup 1.0000x reference)
//
#include <hip/hip_runtime.h>

typedef __attribute__((ext_vector_type(8))) short bf16x8;
typedef __attribute__((ext_vector_type(4))) float f32x4;

#define HH 8
#define DD 32
#define NB 512
#define BS 128
#define LQP 136   // QP / Vt row stride (elements): 128 + 8 pad -> 4-bank row shift
#define LKB 40    // Kb row stride (elements): 32 + 8 pad

__device__ __forceinline__ unsigned int f2bf(float f) {
    unsigned int u = __float_as_uint(f);
    u += 0x7fffu + ((u >> 16) & 1u);   // RNE
    return u >> 16;
}
__device__ __forceinline__ unsigned int pk2(float a, float b) {
    return f2bf(a) | (f2bf(b) << 16);
}

__global__ __launch_bounds__(256, 2) void battn_kernel(
    const float* __restrict__ Qg, const float* __restrict__ Kg,
    const float* __restrict__ Vg, const int* __restrict__ SB,
    float* __restrict__ Og)
{
    __shared__ unsigned short Kb[BS * LKB];   // K  bf16 [key][d]
    __shared__ unsigned short QP[BS * LQP];   // Q bf16 [query][d] then P bf16 [query][key] (wave-private rows)
    __shared__ unsigned short Vt[DD * LQP];   // V  bf16 [d][key] (transposed)
    __shared__ float linv[BS];

    const int bid = blockIdx.x;
    const int h = bid & 7;
    const int n = (bid >> 3) & (NB - 1);
    const int b = bid >> 12;
    const int tid = threadIdx.x;

    const int base = ((b * 65536 + n * BS) * HH + h) * DD;

    // ---------------- staging: global fp32 -> LDS bf16 ----------------
    {
        const int tok = tid >> 1;
        const int half = tid & 1;
        const int go = base + tok * (HH * DD) + half * 16;
        const float4* qv = (const float4*)(Qg + go);
        const float4* kv = (const float4*)(Kg + go);
        float4 a0 = qv[0], a1 = qv[1], a2 = qv[2], a3 = qv[3];
        float4 c0 = kv[0], c1 = kv[1], c2 = kv[2], c3 = kv[3];

        const int vtok = tid & 127;
        const int vd0 = (tid >> 7) * 16;
        const float4* vv = (const float4*)(Vg + base + vtok * (HH * DD) + vd0);
        float4 v0 = vv[0], v1 = vv[1], v2 = vv[2], v3 = vv[3];

        // fold softmax scale AND log2(e) into Q so scores are in exp2 domain
        const float cs = 0.17677669529663687f * 1.4426950408889634f;
        uint4* qd = (uint4*)(QP + tok * LQP + half * 16);
        qd[0] = make_uint4(pk2(a0.x*cs,a0.y*cs), pk2(a0.z*cs,a0.w*cs),
                           pk2(a1.x*cs,a1.y*cs), pk2(a1.z*cs,a1.w*cs));
        qd[1] = make_uint4(pk2(a2.x*cs,a2.y*cs), pk2(a2.z*cs,a2.w*cs),
                           pk2(a3.x*cs,a3.y*cs), pk2(a3.z*cs,a3.w*cs));
        uint4* kd = (uint4*)(Kb + tok * LKB + half * 16);
        kd[0] = make_uint4(pk2(c0.x,c0.y), pk2(c0.z,c0.w), pk2(c1.x,c1.y), pk2(c1.z,c1.w));
        kd[1] = make_uint4(pk2(c2.x,c2.y), pk2(c2.z,c2.w), pk2(c3.x,c3.y), pk2(c3.z,c3.w));

        float vf[16] = {v0.x,v0.y,v0.z,v0.w, v1.x,v1.y,v1.z,v1.w,
                        v2.x,v2.y,v2.z,v2.w, v3.x,v3.y,v3.z,v3.w};
        #pragma unroll
        for (int j = 0; j < 16; ++j)
            Vt[(vd0 + j) * LQP + vtok] = (unsigned short)f2bf(vf[j]);
    }
    __syncthreads();

    const int sb = (b * NB + n) * 2;
    const int st = SB[sb], en = SB[sb + 1];
    const int kbase = n * BS;

    const int lane = tid & 63;
    const int w = tid >> 6;        // wave id: owns queries [w*32, w*32+32)
    const int l15 = lane & 15;
    const int quad = lane >> 4;
    const int q0row = w * 32;

    // B-operand fragments (Q rows of this wave): lane holds Q[q0+l15][quad*8 .. +7]
    bf16x8 qf0 = *(const bf16x8*)(QP + (q0row + l15) * LQP + quad * 8);
    bf16x8 qf1 = *(const bf16x8*)(QP + (q0row + 16 + l15) * LQP + quad * 8);

    const f32x4 z = {0.f, 0.f, 0.f, 0.f};
    // S^T tiles: A = K (M=key), B = Q (N=query); one MFMA covers full D=32 contraction
    f32x4 acc0[8], acc1[8];
    #pragma unroll
    for (int kt = 0; kt < 8; ++kt) {
        bf16x8 kf = *(const bf16x8*)(Kb + (kt * 16 + l15) * LKB + quad * 8);
        acc0[kt] = __builtin_amdgcn_mfma_f32_16x16x32_bf16(kf, qf0, z, 0, 0, 0);
        acc1[kt] = __builtin_amdgcn_mfma_f32_16x16x32_bf16(kf, qf1, z, 0, 0, 0);
    }

    // mask + row max (C layout: row=key=quad*4+r, col=query=l15)
    float m0 = -1.0e30f, m1 = -1.0e30f;
    #pragma unroll
    for (int kt = 0; kt < 8; ++kt) {
        #pragma unroll
        for (int r = 0; r < 4; ++r) {
            const int ap = kbase + kt * 16 + quad * 4 + r;
            const bool kv = (ap >= st) && (ap < en);
            float s0 = kv ? acc0[kt][r] : -1.0e30f;
            float s1 = kv ? acc1[kt][r] : -1.0e30f;
            acc0[kt][r] = s0; acc1[kt][r] = s1;
            m0 = fmaxf(m0, s0); m1 = fmaxf(m1, s1);
        }
    }
    m0 = fmaxf(m0, __shfl_xor(m0, 16));
    m0 = fmaxf(m0, __shfl_xor(m0, 32));
    m1 = fmaxf(m1, __shfl_xor(m1, 16));
    m1 = fmaxf(m1, __shfl_xor(m1, 32));

    // p = exp2(s - m); write P (bf16) into this wave's own QP rows; 4 consecutive keys per reg -> b64 store
    float s0sum = 0.f, s1sum = 0.f;
    #pragma unroll
    for (int kt = 0; kt < 8; ++kt) {
        float p0[4], p1[4];
        #pragma unroll
        for (int r = 0; r < 4; ++r) {
            p0[r] = exp2f(acc0[kt][r] - m0);
            p1[r] = exp2f(acc1[kt][r] - m1);
            s0sum += p0[r]; s1sum += p1[r];
        }
        *(uint2*)(QP + (q0row + l15) * LQP + kt * 16 + quad * 4) =
            make_uint2(pk2(p0[0], p0[1]), pk2(p0[2], p0[3]));
        *(uint2*)(QP + (q0row + 16 + l15) * LQP + kt * 16 + quad * 4) =
            make_uint2(pk2(p1[0], p1[1]), pk2(p1[2], p1[3]));
    }
    s0sum += __shfl_xor(s0sum, 16);
    s0sum += __shfl_xor(s0sum, 32);
    s1sum += __shfl_xor(s1sum, 16);
    s1sum += __shfl_xor(s1sum, 32);
    if (quad == 0) {
        linv[q0row + l15] = 1.0f / s0sum;
        linv[q0row + 16 + l15] = 1.0f / s1sum;
    }
    __syncthreads();   // also a compiler memory fence for the QP type-punned write->read

    // O = P (A, M=query) * Vt (B: B[k=key][n=d] = Vt[d][key])
    f32x4 o00 = z, o01 = z, o10 = z, o11 = z;
    #pragma unroll
    for (int kc = 0; kc < 4; ++kc) {
        const int ko = kc * 32 + quad * 8;
        bf16x8 p0  = *(const bf16x8*)(QP + (q0row + l15) * LQP + ko);
        bf16x8 p1  = *(const bf16x8*)(QP + (q0row + 16 + l15) * LQP + ko);
        bf16x8 vv0 = *(const bf16x8*)(Vt + l15 * LQP + ko);
        bf16x8 vv1 = *(const bf16x8*)(Vt + (16 + l15) * LQP + ko);
        o00 = __builtin_amdgcn_mfma_f32_16x16x32_bf16(p0, vv0, o00, 0, 0, 0);
        o01 = __builtin_amdgcn_mfma_f32_16x16x32_bf16(p0, vv1, o01, 0, 0, 0);
        o10 = __builtin_amdgcn_mfma_f32_16x16x32_bf16(p1, vv0, o10, 0, 0, 0);
        o11 = __builtin_amdgcn_mfma_f32_16x16x32_bf16(p1, vv1, o11, 0, 0, 0);
    }

    // epilogue: normalize, gate invalid queries to zero, store fp32
    #pragma unroll
    for (int mt = 0; mt < 2; ++mt) {
        #pragma unroll
        for (int r = 0; r < 4; ++r) {
            const int q = q0row + mt * 16 + quad * 4 + r;
            const int ap = kbase + q;
            const float iv = ((ap >= st) && (ap < en)) ? linv[q] : 0.f;
            const int go = base + q * (HH * DD);
            const f32x4& t0 = mt ? o10 : o00;
            const f32x4& t1 = mt ? o11 : o01;
            Og[go + l15] = t0[r] * iv;
            Og[go + 16 + l15] = t1[r] * iv;
        }
    }
}

extern "C" void kernel_launch(void* const* d_in, const int* in_sizes, int n_in,
                              void* d_out, int out_size, void* d_ws, size_t ws_size,
                              hipStream_t stream) {
    const float* Q = (const float*)d_in[0];
    const float* K = (const float*)d_in[1];
    const float* V = (const float*)d_in[2];
    const int* SB  = (const int*)d_in[3];
    float* O = (float*)d_out;
    battn_kernel<<<dim3(8192), dim3(256), 0, stream>>>(Q, K, V, SB, O);
}